// Round 10
// baseline (11210.573 us; speedup 1.0000x reference)
//
#include <hip/hip_runtime.h>
#include <math.h>

#define B_      8
#define N_      16384
#define CIN_    128
#define COUT_   256
#define NS_     4096

typedef unsigned long long u64;

// XLA-CPU-contracted distance: fma(dz,dz, fma(dy,dy, dx*dx)) — bit-exact vs gold.
static __device__ __forceinline__ float sqdist_xla(float px, float py, float pz,
                                                   float cx, float cy, float cz) {
  float dx = __fsub_rn(px, cx);
  float dy = __fsub_rn(py, cy);
  float dz = __fsub_rn(pz, cz);
  return __fmaf_rn(dz, dz, __fmaf_rn(dy, dy, __fmul_rn(dx, dx)));
}

static __device__ __forceinline__ unsigned spread3(unsigned v) {
  v &= 0x3FF;
  v = (v | (v << 16)) & 0x030000FF;
  v = (v | (v <<  8)) & 0x0300F00F;
  v = (v | (v <<  4)) & 0x030C30C3;
  v = (v | (v <<  2)) & 0x09249249;
  return v;
}

// Blocks 0..7: exact FPS with wave-uniform sub-chunk pruning (morton-sorted).
// Blocks 8..15: full Gram G = F^T F + column sums S per batch (hidden under FPS).
__global__ __launch_bounds__(1024, 4) void k1_fps_gram(
    const float* __restrict__ points, const float* __restrict__ features,
    float* __restrict__ outP, int* __restrict__ idxw,
    float* __restrict__ Gred, float* __restrict__ Sred)
{
  __shared__ __align__(16) char LDSB[131072 + 512 + 16];
  const int tid = threadIdx.x;

  if (blockIdx.x < B_) {
    // ================= FPS =================
    const int b = blockIdx.x;
    const float* __restrict__ P = points + (size_t)b * N_ * 3;
    float2* __restrict__ sXY  = (float2*)LDSB;           // sorted xy (aliases KEYS)
    u64*    __restrict__ KEYS = (u64*)LDSB;
    char*   __restrict__ SLOT = LDSB + 131072;           // 16 slots x 32B {key,x,y,z}
    float*  __restrict__ cent = (float*)(LDSB + 131072 + 512);
    const int lane  = tid & 63;
    const int wid   = tid >> 6;     // 0..15
    const int wbase = wid << 10;    // wave owns 1024 sorted points

    // ---- morton keys: key = morton30<<14 | origidx ----
    for (int k = 0; k < 16; ++k) {
      const int n = k * 1024 + tid;
      const float x = P[3*n+0], y = P[3*n+1], z = P[3*n+2];
      const unsigned mx = min(1023, max(0, (int)((x + 6.0f) * 85.333336f)));
      const unsigned my = min(1023, max(0, (int)((y + 6.0f) * 85.333336f)));
      const unsigned mz = min(1023, max(0, (int)((z + 6.0f) * 85.333336f)));
      const unsigned m  = spread3(mx) | (spread3(my) << 1) | (spread3(mz) << 2);
      KEYS[n] = ((u64)m << 14) | (u64)n;
    }

    // ---- bitonic sort ascending ----
    for (unsigned kk = 2; kk <= (unsigned)N_; kk <<= 1)
      for (unsigned j = kk >> 1; j > 0; j >>= 1) {
        __syncthreads();
        #pragma unroll 4
        for (unsigned t = 0; t < 16; ++t) {
          const unsigned i = t * 1024 + tid;
          const unsigned l = i ^ j;
          if (l > i) {
            const u64 a = KEYS[i], c = KEYS[l];
            const bool asc = ((i & kk) == 0);
            if ((a > c) == asc) { KEYS[i] = c; KEYS[l] = a; }
          }
        }
      }
    __syncthreads();

    // ---- read my 16 sorted keys (pos = wbase + c*256 + k*64 + lane) ----
    int myo[16];
    #pragma unroll
    for (int idx = 0; idx < 16; ++idx) {
      const int pos = wbase + (idx>>2)*256 + (idx&3)*64 + lane;
      myo[idx] = (int)(KEYS[pos] & 0x3FFF);
    }
    __syncthreads();   // all key reads done before xy overwrite

    // ---- gather: xy -> LDS (same slots), z -> regs ----
    float z_[16];
    #pragma unroll
    for (int idx = 0; idx < 16; ++idx) {
      const int o   = myo[idx];
      const int pos = wbase + (idx>>2)*256 + (idx&3)*64 + lane;
      sXY[pos] = make_float2(P[3*o+0], P[3*o+1]);
      z_[idx]  = P[3*o+2];
    }
    #pragma unroll
    for (int idx = 0; idx < 16; ++idx) asm volatile("" : "+v"(z_[idx]));
    // centroid: strict sequential f32 (reference emission order), *2^-14 exact
    if (tid < 3) {
      const int c = tid;
      float acc = P[c];
      for (int n = 1; n < N_; ++n) acc = __fadd_rn(acc, P[3*n + c]);
      cent[c] = __fmul_rn(acc, 6.103515625e-05f);
    }
    __syncthreads();

    // ---- per-sub-chunk bounding spheres (4 x 256 pts per wave) ----
    float sccx[4], sccy[4], sccz[4], scr[4];
    #pragma unroll
    for (int c = 0; c < 4; ++c) {
      float xmn=1e30f, xmx=-1e30f, ymn=1e30f, ymx=-1e30f, zmn=1e30f, zmx=-1e30f;
      #pragma unroll
      for (int k = 0; k < 4; ++k) {
        const int pos = wbase + c*256 + k*64 + lane;
        const float2 xy = sXY[pos];
        const float zz = z_[c*4+k];
        xmn=fminf(xmn,xy.x); xmx=fmaxf(xmx,xy.x);
        ymn=fminf(ymn,xy.y); ymx=fmaxf(ymx,xy.y);
        zmn=fminf(zmn,zz);   zmx=fmaxf(zmx,zz);
      }
      #pragma unroll
      for (int off = 32; off > 0; off >>= 1) {
        xmn=fminf(xmn,__shfl_xor(xmn,off)); xmx=fmaxf(xmx,__shfl_xor(xmx,off));
        ymn=fminf(ymn,__shfl_xor(ymn,off)); ymx=fmaxf(ymx,__shfl_xor(ymx,off));
        zmn=fminf(zmn,__shfl_xor(zmn,off)); zmx=fmaxf(zmx,__shfl_xor(zmx,off));
      }
      const float cx = 0.5f*(xmn+xmx), cy = 0.5f*(ymn+ymx), cz = 0.5f*(zmn+zmx);
      float r2 = 0.f;
      #pragma unroll
      for (int k = 0; k < 4; ++k) {
        const int pos = wbase + c*256 + k*64 + lane;
        const float2 xy = sXY[pos];
        const float dx = xy.x-cx, dy = xy.y-cy, dz = z_[c*4+k]-cz;
        r2 = fmaxf(r2, dx*dx + dy*dy + dz*dz);
      }
      #pragma unroll
      for (int off = 32; off > 0; off >>= 1) r2 = fmaxf(r2, __shfl_xor(r2, off));
      sccx[c]=cx; sccy[c]=cy; sccz[c]=cz;
      scr[c] = sqrtf(r2) * 1.0005f + 1e-7f;   // certified upper bound on radius
    }

    float dd_[16];
    float ccx, ccy, ccz, cmax;

    // ---- d0 pass: distances to centroid, pick 0 ----
    {
      const float cx0 = cent[0], cy0 = cent[1], cz0 = cent[2];
      #pragma unroll
      for (int idx = 0; idx < 16; ++idx) {
        const int pos = wbase + (idx>>2)*256 + (idx&3)*64 + lane;
        const float2 xy = sXY[pos];
        dd_[idx] = sqdist_xla(xy.x, xy.y, z_[idx], cx0, cy0, cz0);
      }
      float lm = dd_[0];
      #pragma unroll
      for (int k = 1; k < 16; ++k) lm = fmaxf(lm, dd_[k]);
      int bo = 0x7FFFFFFF, bk = 0;
      #pragma unroll
      for (int k = 0; k < 16; ++k) {
        const bool t = (dd_[k] == lm) && (myo[k] < bo);
        bo = t ? myo[k] : bo; bk = t ? k : bk;
      }
      u64 my = ((u64)__float_as_uint(lm) << 32)
             | (u64)(((unsigned)((~bo) & 0x3FFF) << 4) | (unsigned)wid);
      u64 wk = my;
      #pragma unroll
      for (int off = 32; off > 0; off >>= 1) {
        const u64 o = __shfl_xor(wk, off); wk = (o > wk) ? o : wk;
      }
      if (my == wk) {                     // unique winner lane writes slot
        const int pos = wbase + (bk>>2)*256 + (bk&3)*64 + lane;
        const float2 xy = sXY[pos];
        float zz = z_[0];
        #pragma unroll
        for (int k = 1; k < 16; ++k) zz = (bk == k) ? z_[k] : zz;
        *(u64*)(SLOT + wid*32) = wk;
        ((float*)(SLOT + wid*32))[2] = xy.x;
        ((float*)(SLOT + wid*32))[3] = xy.y;
        ((float*)(SLOT + wid*32))[4] = zz;
      }
    }
    __syncthreads();                      // b1: slots visible
    {
      u64 wk = *(const u64*)(SLOT + (lane & 15)*32);
      #pragma unroll
      for (int off = 8; off > 0; off >>= 1) {
        const u64 o = __shfl_xor(wk, off); wk = (o > wk) ? o : wk;
      }
      const int wsl = (int)(wk & 15);
      const float* sp = (const float*)(SLOT + wsl*32);
      ccx = sp[2]; ccy = sp[3]; ccz = sp[4];
      if (tid == 0) {
        const size_t ob = (size_t)b * NS_;
        outP[ob*3+0]=ccx; outP[ob*3+1]=ccy; outP[ob*3+2]=ccz;
        idxw[ob] = (int)((~(wk >> 4)) & 0x3FFFULL);
      }
    }
    __syncthreads();                      // b2: reads done before next writes
    #pragma unroll
    for (int k = 0; k < 16; ++k) dd_[k] = 1e10f;    // reference init
    cmax = 1e10f;

    // ---- main loop ----
    for (int s = 1; s < NS_; ++s) {
      bool dirty = false;
      const float thr = cmax * 1.00002f;
      #pragma unroll
      for (int c = 0; c < 4; ++c) {
        const float Dx = ccx - sccx[c], Dy = ccy - sccy[c], Dz = ccz - sccz[c];
        const float a = sqrtf(Dx*Dx + Dy*Dy + Dz*Dz) * 0.999999f - scr[c];
        if (!((a > 0.0f) && (a*a > thr))) {     // conservative: scan when in doubt
          #pragma unroll
          for (int k = 0; k < 4; ++k) {
            const int pos = wbase + c*256 + k*64 + lane;
            const float2 xy = sXY[pos];
            const float d = sqdist_xla(xy.x, xy.y, z_[c*4+k], ccx, ccy, ccz);
            dd_[c*4+k] = fminf(dd_[c*4+k], d);
          }
          dirty = true;
        }
      }
      if (dirty) {                        // recompute this wave's candidate
        float lm = dd_[0];
        #pragma unroll
        for (int k = 1; k < 16; ++k) lm = fmaxf(lm, dd_[k]);
        int bo = 0x7FFFFFFF, bk = 0;
        #pragma unroll
        for (int k = 0; k < 16; ++k) {
          const bool t = (dd_[k] == lm) && (myo[k] < bo);
          bo = t ? myo[k] : bo; bk = t ? k : bk;
        }
        u64 my = ((u64)__float_as_uint(lm) << 32)
               | (u64)(((unsigned)((~bo) & 0x3FFF) << 4) | (unsigned)wid);
        u64 wk = my;
        #pragma unroll
        for (int off = 32; off > 0; off >>= 1) {
          const u64 o = __shfl_xor(wk, off); wk = (o > wk) ? o : wk;
        }
        if (my == wk) {
          const int pos = wbase + (bk>>2)*256 + (bk&3)*64 + lane;
          const float2 xy = sXY[pos];
          float zz = z_[0];
          #pragma unroll
          for (int k = 1; k < 16; ++k) zz = (bk == k) ? z_[k] : zz;
          *(u64*)(SLOT + wid*32) = wk;
          ((float*)(SLOT + wid*32))[2] = xy.x;
          ((float*)(SLOT + wid*32))[3] = xy.y;
          ((float*)(SLOT + wid*32))[4] = zz;
        }
        cmax = __uint_as_float((unsigned)(wk >> 32));
      }
      __syncthreads();                    // b1
      {
        u64 wk = *(const u64*)(SLOT + (lane & 15)*32);
        #pragma unroll
        for (int off = 8; off > 0; off >>= 1) {
          const u64 o = __shfl_xor(wk, off); wk = (o > wk) ? o : wk;
        }
        const int wsl = (int)(wk & 15);
        const float* sp = (const float*)(SLOT + wsl*32);
        ccx = sp[2]; ccy = sp[3]; ccz = sp[4];
        if (tid == 0) {
          const size_t ob = (size_t)b * NS_ + s;
          outP[ob*3+0]=ccx; outP[ob*3+1]=ccy; outP[ob*3+2]=ccz;
          idxw[ob] = (int)((~(wk >> 4)) & 0x3FFFULL);
        }
      }
      __syncthreads();                    // b2
    }
  } else {
    // ================= Gram (one block per batch) =================
    float* __restrict__ Lf = (float*)LDSB;     // [32][128]
    const int b = (int)blockIdx.x - B_;
    float acc[4][4];
    #pragma unroll
    for (int i = 0; i < 4; ++i)
      #pragma unroll
      for (int j = 0; j < 4; ++j) acc[i][j] = 0.f;
    float sacc = 0.f;
    const int ti = tid >> 5;   // 0..31
    const int tj = tid & 31;   // 0..31
    const float* fb = features + (size_t)b * N_ * CIN_;
    for (int t32 = 0; t32 < N_/32; ++t32) {
      const float4 v0 = *(const float4*)(fb + ((size_t)t32 * 32 + ti) * CIN_ + tj * 4);
      __syncthreads();
      *(float4*)&Lf[ti*128 + tj*4] = v0;
      __syncthreads();
      #pragma unroll 4
      for (int r = 0; r < 32; ++r) {
        const float4 a4 = *(const float4*)&Lf[r*128 + ti*4];
        const float4 b4 = *(const float4*)&Lf[r*128 + tj*4];
        const float av[4] = {a4.x, a4.y, a4.z, a4.w};
        const float bw[4] = {b4.x, b4.y, b4.z, b4.w};
        #pragma unroll
        for (int i = 0; i < 4; ++i)
          #pragma unroll
          for (int j = 0; j < 4; ++j) acc[i][j] = fmaf(av[i], bw[j], acc[i][j]);
      }
      if (tid < 128) {
        #pragma unroll 8
        for (int r = 0; r < 32; ++r) sacc += Lf[r*128 + tid];
      }
    }
    float* gp = Gred + (size_t)b * (CIN_*CIN_);
    #pragma unroll
    for (int i = 0; i < 4; ++i)
      #pragma unroll
      for (int j = 0; j < 4; ++j)
        gp[(ti*4+i)*CIN_ + tj*4 + j] = acc[i][j];
    if (tid < 128) Sred[b*CIN_ + tid] = sacc;
  }
}

// per (b,o): mu-b = w.S/N ; var = (wGw + 2 b w.S)/N + b^2 - mu^2 ; scale = 1/sqrt(var+eps)
__global__ __launch_bounds__(128) void k2b_stats(
    const float* __restrict__ Gred, const float* __restrict__ Sred,
    const float* __restrict__ W, const float* __restrict__ bias,
    float* __restrict__ stats)
{
  const int b = blockIdx.x >> 8;
  const int o = blockIdx.x & 255;
  const int tid = threadIdx.x;
  __shared__ float sw[CIN_];
  __shared__ float r1[CIN_], r2[CIN_];
  sw[tid] = W[(size_t)o*CIN_ + tid];
  __syncthreads();
  const float* gr = Gred + (size_t)b*CIN_*CIN_ + (size_t)tid*CIN_;
  float g = 0.f;
  #pragma unroll 8
  for (int j = 0; j < CIN_; ++j) g = fmaf(gr[j], sw[j], g);
  r1[tid] = g * sw[tid];
  r2[tid] = sw[tid] * Sred[b*CIN_ + tid];
  __syncthreads();
  for (int stp = 64; stp > 0; stp >>= 1) {
    if (tid < stp) { r1[tid] += r1[tid+stp]; r2[tid] += r2[tid+stp]; }
    __syncthreads();
  }
  if (tid == 0) {
    const float wGw = r1[0], wS = r2[0], bo = bias[o];
    const float invN = 1.0f / (float)N_;
    const float mu  = wS*invN + bo;
    const float ex2 = (wGw + 2.0f*bo*wS)*invN + bo*bo;
    float var = ex2 - mu*mu;
    var = fmaxf(var, 0.0f);
    const float sc = 1.0f / sqrtf(var + 1e-5f);
    stats[((size_t)(b*COUT_ + o))*2 + 0] = wS*invN;  // mu - bias
    stats[((size_t)(b*COUT_ + o))*2 + 1] = sc;
  }
}

// recompute GEMM at sampled rows only, apply norm + relu
__global__ __launch_bounds__(256) void k3_out(
    const float* __restrict__ features, const float* __restrict__ W,
    const int* __restrict__ idxw, const float* __restrict__ stats,
    float* __restrict__ outF)
{
  const int tid = threadIdx.x;
  const int b  = blockIdx.x >> 8;
  const int r  = blockIdx.x & 255;
  const int st = r >> 2, ot = r & 3;
  const int s0 = st * 64, o0 = ot * 64;

  __shared__ float Fs[64][129];
  __shared__ float Wt[64][129];
  __shared__ int   sIdx[64];
  __shared__ float sSub[64], sSc[64];

  if (tid < 64) sIdx[tid] = idxw[b*NS_ + s0 + tid];
  if (tid >= 64 && tid < 128) {
    const int oo = tid - 64;
    sSub[oo] = stats[((size_t)(b*COUT_ + o0 + oo))*2 + 0];
    sSc[oo]  = stats[((size_t)(b*COUT_ + o0 + oo))*2 + 1];
  }
  __syncthreads();
  {
    const int row = tid >> 2;   // 0..63
    const int q   = tid & 3;
    const float* fsrc = features + ((size_t)b*N_ + sIdx[row]) * CIN_;
    const float* wsrc = W + (size_t)(o0 + row) * CIN_;
    #pragma unroll
    for (int v = 0; v < 8; ++v) {
      const int c = q*4 + v*16;
      const float4 fv = *(const float4*)(fsrc + c);
      const float4 wv = *(const float4*)(wsrc + c);
      Fs[row][c+0]=fv.x; Fs[row][c+1]=fv.y; Fs[row][c+2]=fv.z; Fs[row][c+3]=fv.w;
      Wt[row][c+0]=wv.x; Wt[row][c+1]=wv.y; Wt[row][c+2]=wv.z; Wt[row][c+3]=wv.w;
    }
  }
  __syncthreads();

  const int ts = tid >> 4, to = tid & 15;
  float acc[4][4];
  #pragma unroll
  for (int i = 0; i < 4; ++i)
    #pragma unroll
    for (int j = 0; j < 4; ++j) acc[i][j] = 0.f;

  #pragma unroll 4
  for (int k = 0; k < CIN_; ++k) {
    const float a0 = Fs[ts*4+0][k], a1 = Fs[ts*4+1][k], a2 = Fs[ts*4+2][k], a3 = Fs[ts*4+3][k];
    const float w0 = Wt[to*4+0][k], w1 = Wt[to*4+1][k], w2 = Wt[to*4+2][k], w3 = Wt[to*4+3][k];
    acc[0][0]=fmaf(a0,w0,acc[0][0]); acc[0][1]=fmaf(a0,w1,acc[0][1]); acc[0][2]=fmaf(a0,w2,acc[0][2]); acc[0][3]=fmaf(a0,w3,acc[0][3]);
    acc[1][0]=fmaf(a1,w0,acc[1][0]); acc[1][1]=fmaf(a1,w1,acc[1][1]); acc[1][2]=fmaf(a1,w2,acc[1][2]); acc[1][3]=fmaf(a1,w3,acc[1][3]);
    acc[2][0]=fmaf(a2,w0,acc[2][0]); acc[2][1]=fmaf(a2,w1,acc[2][1]); acc[2][2]=fmaf(a2,w2,acc[2][2]); acc[2][3]=fmaf(a2,w3,acc[2][3]);
    acc[3][0]=fmaf(a3,w0,acc[3][0]); acc[3][1]=fmaf(a3,w1,acc[3][1]); acc[3][2]=fmaf(a3,w2,acc[3][2]); acc[3][3]=fmaf(a3,w3,acc[3][3]);
  }

  #pragma unroll
  for (int i = 0; i < 4; ++i) {
    float4 o4;
    o4.x = fmaxf((acc[i][0] - sSub[to*4+0]) * sSc[to*4+0], 0.f);
    o4.y = fmaxf((acc[i][1] - sSub[to*4+1]) * sSc[to*4+1], 0.f);
    o4.z = fmaxf((acc[i][2] - sSub[to*4+2]) * sSc[to*4+2], 0.f);
    o4.w = fmaxf((acc[i][3] - sSub[to*4+3]) * sSc[to*4+3], 0.f);
    *(float4*)&outF[((size_t)b*NS_ + s0 + ts*4 + i)*COUT_ + o0 + to*4] = o4;
  }
}

extern "C" void kernel_launch(void* const* d_in, const int* in_sizes, int n_in,
                              void* d_out, int out_size, void* d_ws, size_t ws_size,
                              hipStream_t stream) {
  (void)in_sizes; (void)n_in; (void)out_size; (void)ws_size;
  const float* points   = (const float*)d_in[0];
  const float* features = (const float*)d_in[1];
  const float* W        = (const float*)d_in[2];
  const float* bias     = (const float*)d_in[3];
  float* out  = (float*)d_out;
  float* outP = out;
  float* outF = out + (size_t)B_*NS_*3;

  char* ws = (char*)d_ws;
  int*   idxw  = (int*)  (ws + 0);        // 131072 B
  float* Gred  = (float*)(ws + 131072);   // 524288 B
  float* Sred  = (float*)(ws + 655360);   // 4096 B
  float* stats = (float*)(ws + 659456);   // 16384 B

  k1_fps_gram<<<dim3(B_ + B_),  dim3(1024), 0, stream>>>(points, features, outP, idxw, Gred, Sred);
  k2b_stats  <<<dim3(B_*COUT_), dim3(CIN_), 0, stream>>>(Gred, Sred, W, bias, stats);
  k3_out     <<<dim3(B_*256),   dim3(256),  0, stream>>>(features, W, idxw, stats, outF);
}

// Round 11
// 9230.573 us; speedup vs baseline: 1.2145x; 1.2145x over previous
//
#include <hip/hip_runtime.h>
#include <math.h>

#define B_      8
#define N_      16384
#define CIN_    128
#define COUT_   256
#define NS_     4096
#define PPT     32      // points per thread (512 threads)

typedef unsigned long long u64;

#define RPT32(X) X(0) X(1) X(2) X(3) X(4) X(5) X(6) X(7) \
                 X(8) X(9) X(10) X(11) X(12) X(13) X(14) X(15) \
                 X(16) X(17) X(18) X(19) X(20) X(21) X(22) X(23) \
                 X(24) X(25) X(26) X(27) X(28) X(29) X(30) X(31)

// XLA-CPU-contracted distance: fma(dz,dz, fma(dy,dy, dx*dx)) — bit-exact vs gold.
static __device__ __forceinline__ float sqdist_xla(float px, float py, float pz,
                                                   float cx, float cy, float cz) {
  float dx = __fsub_rn(px, cx);
  float dy = __fsub_rn(py, cy);
  float dz = __fsub_rn(pz, cz);
  return __fmaf_rn(dz, dz, __fmaf_rn(dy, dy, __fmul_rn(dx, dx)));
}

// Blocks 0..7: FPS — 512 thr, 32 pts/thr, ALL state in named scalar VGPRs.
// amdgpu_waves_per_eu(2,2) pins the allocator budget to 256 VGPR (the r5-r10
// failure was the allocator targeting high occupancy and spilling the state).
// Blocks 8..15: full Gram G = F^T F + column sums S per batch.
__global__ void
__attribute__((amdgpu_flat_work_group_size(512, 512), amdgpu_waves_per_eu(2, 2)))
k1_fps_gram(
    const float* __restrict__ points, const float* __restrict__ features,
    float* __restrict__ outP, int* __restrict__ idxw,
    float* __restrict__ Gred, float* __restrict__ Sred)
{
  __shared__ u64   slotKey[2][8];
  __shared__ float slotC[2][8][4];
  __shared__ float cent[3];
  __shared__ __align__(16) float Lf[32][128];   // Gram staging only
  const int tid = threadIdx.x;

  if (blockIdx.x < B_) {
    // ================= FPS =================
    const int b = blockIdx.x;
    const float* __restrict__ P = points + (size_t)b * N_ * 3;
    const int base = tid * PPT;
    const int lane = tid & 63;
    const int wid  = tid >> 6;    // 0..7

    #define DECLP(i) float x##i, y##i, z##i, dd##i;
    RPT32(DECLP)
    #define LOADP(i) x##i = P[3*(base+(i))+0]; \
                     y##i = P[3*(base+(i))+1]; \
                     z##i = P[3*(base+(i))+2];
    RPT32(LOADP)
    #define PINP(i) asm volatile("" : "+v"(x##i), "+v"(y##i), "+v"(z##i));
    RPT32(PINP)

    // centroid: strict sequential f32 (reference emission order), *2^-14 exact
    if (tid < 3) {
      const int c = tid;
      float acc = P[c];
      for (int n = 1; n < N_; ++n) acc = __fadd_rn(acc, P[3*n + c]);
      cent[c] = __fmul_rn(acc, 6.103515625e-05f);
    }
    __syncthreads();

    float ccx, ccy, ccz;

    #define PICKI(i) { const bool e = (lk == (i)); \
      sx = e ? x##i : sx; sy = e ? y##i : sy; sz = e ? z##i : sz; }

    // one barrier per iteration; parity slots; winner-lane coord extract.
    #define SELECT_FAR(pp, ss) do { \
      const int gid = base + lk; \
      const u64 my = ((u64)__float_as_uint(lm) << 32) \
                   | ((u64)((unsigned)(~gid) & 0x3FFFu) << 4) | (unsigned)wid; \
      u64 wk = my; \
      _Pragma("unroll") \
      for (int off = 32; off > 0; off >>= 1) { \
        const u64 o = __shfl_xor(wk, off); wk = (o > wk) ? o : wk; } \
      if (my == wk) { \
        float sx = x0, sy = y0, sz = z0; \
        RPT32(PICKI) \
        slotKey[pp][wid] = wk; \
        slotC[pp][wid][0] = sx; slotC[pp][wid][1] = sy; slotC[pp][wid][2] = sz; \
      } \
      __syncthreads(); \
      u64 bk2 = slotKey[pp][lane & 7]; \
      _Pragma("unroll") \
      for (int off = 4; off > 0; off >>= 1) { \
        const u64 o = __shfl_xor(bk2, off); bk2 = (o > bk2) ? o : bk2; } \
      const int wsl = (int)(bk2 & 7); \
      ccx = slotC[pp][wsl][0]; ccy = slotC[pp][wsl][1]; ccz = slotC[pp][wsl][2]; \
      if (tid == 0) { \
        const size_t ob = (size_t)b * NS_ + (ss); \
        outP[ob*3+0] = ccx; outP[ob*3+1] = ccy; outP[ob*3+2] = ccz; \
        idxw[ob] = (int)((~(bk2 >> 4)) & 0x3FFFULL); \
      } \
    } while (0)

    // ---- d0 pass: distance to centroid, first-occurrence argmax ----
    {
      const float cx0 = cent[0], cy0 = cent[1], cz0 = cent[2];
      float lm; int lk = 0;
      lm = sqdist_xla(x0, y0, z0, cx0, cy0, cz0); dd0 = lm;
      #define SCAN0(i) if ((i) > 0) { \
        const float d = sqdist_xla(x##i, y##i, z##i, cx0, cy0, cz0); \
        dd##i = d; const bool bt = (d > lm); \
        lk = bt ? (i) : lk; lm = bt ? d : lm; }
      RPT32(SCAN0)
      SELECT_FAR(0, 0);
    }
    #define INITD(i) dd##i = 1e10f;
    RPT32(INITD)

    // ---- main loop ----
    for (int s = 1; s < NS_; ++s) {
      float lm = -1.0f; int lk = 0;
      #define SCANU(i) { \
        const float d  = sqdist_xla(x##i, y##i, z##i, ccx, ccy, ccz); \
        const float nd = fminf(dd##i, d); dd##i = nd; \
        const bool bt = (nd > lm); \
        lk = bt ? (i) : lk; lm = bt ? nd : lm; }
      RPT32(SCANU)
      SELECT_FAR(s & 1, s);
    }
  } else {
    // ================= Gram (one block per batch, 512 threads) =================
    const int b = (int)blockIdx.x - B_;
    float acc[4][8];
    #pragma unroll
    for (int i = 0; i < 4; ++i)
      #pragma unroll
      for (int j = 0; j < 8; ++j) acc[i][j] = 0.f;
    float sacc = 0.f;
    const int ti = tid >> 4;   // 0..31
    const int tj = tid & 15;   // 0..15
    const float* fb = features + (size_t)b * N_ * CIN_;
    for (int t32 = 0; t32 < N_/32; ++t32) {
      const float* src = fb + ((size_t)t32 * 32 + ti) * CIN_ + tj * 8;
      const float4 v0 = *(const float4*)(src);
      const float4 v1 = *(const float4*)(src + 4);
      __syncthreads();
      *(float4*)&Lf[ti][tj*8]     = v0;
      *(float4*)&Lf[ti][tj*8 + 4] = v1;
      __syncthreads();
      #pragma unroll 4
      for (int r = 0; r < 32; ++r) {
        const float4 a4  = *(const float4*)&Lf[r][ti*4];
        const float4 b40 = *(const float4*)&Lf[r][tj*8];
        const float4 b41 = *(const float4*)&Lf[r][tj*8+4];
        const float av[4] = {a4.x, a4.y, a4.z, a4.w};
        const float bw[8] = {b40.x, b40.y, b40.z, b40.w, b41.x, b41.y, b41.z, b41.w};
        #pragma unroll
        for (int i = 0; i < 4; ++i)
          #pragma unroll
          for (int j = 0; j < 8; ++j) acc[i][j] = fmaf(av[i], bw[j], acc[i][j]);
      }
      if (tid < 128) {
        #pragma unroll 8
        for (int r = 0; r < 32; ++r) sacc += Lf[r][tid];
      }
    }
    float* gp = Gred + (size_t)b * (CIN_*CIN_);
    #pragma unroll
    for (int i = 0; i < 4; ++i)
      #pragma unroll
      for (int j = 0; j < 8; ++j)
        gp[(ti*4+i)*CIN_ + tj*8 + j] = acc[i][j];
    if (tid < 128) Sred[b*CIN_ + tid] = sacc;
  }
}

// per (b,o): mu-b = w.S/N ; var = (wGw + 2 b w.S)/N + b^2 - mu^2 ; scale = 1/sqrt(var+eps)
__global__ __launch_bounds__(128) void k2b_stats(
    const float* __restrict__ Gred, const float* __restrict__ Sred,
    const float* __restrict__ W, const float* __restrict__ bias,
    float* __restrict__ stats)
{
  const int b = blockIdx.x >> 8;
  const int o = blockIdx.x & 255;
  const int tid = threadIdx.x;
  __shared__ float sw[CIN_];
  __shared__ float r1[CIN_], r2[CIN_];
  sw[tid] = W[(size_t)o*CIN_ + tid];
  __syncthreads();
  const float* gr = Gred + (size_t)b*CIN_*CIN_ + (size_t)tid*CIN_;
  float g = 0.f;
  #pragma unroll 8
  for (int j = 0; j < CIN_; ++j) g = fmaf(gr[j], sw[j], g);
  r1[tid] = g * sw[tid];
  r2[tid] = sw[tid] * Sred[b*CIN_ + tid];
  __syncthreads();
  for (int stp = 64; stp > 0; stp >>= 1) {
    if (tid < stp) { r1[tid] += r1[tid+stp]; r2[tid] += r2[tid+stp]; }
    __syncthreads();
  }
  if (tid == 0) {
    const float wGw = r1[0], wS = r2[0], bo = bias[o];
    const float invN = 1.0f / (float)N_;
    const float mu  = wS*invN + bo;
    const float ex2 = (wGw + 2.0f*bo*wS)*invN + bo*bo;
    float var = ex2 - mu*mu;
    var = fmaxf(var, 0.0f);
    const float sc = 1.0f / sqrtf(var + 1e-5f);
    stats[((size_t)(b*COUT_ + o))*2 + 0] = wS*invN;  // mu - bias
    stats[((size_t)(b*COUT_ + o))*2 + 1] = sc;
  }
}

// recompute GEMM at sampled rows only, apply norm + relu
__global__ __launch_bounds__(256) void k3_out(
    const float* __restrict__ features, const float* __restrict__ W,
    const int* __restrict__ idxw, const float* __restrict__ stats,
    float* __restrict__ outF)
{
  const int tid = threadIdx.x;
  const int b  = blockIdx.x >> 8;
  const int r  = blockIdx.x & 255;
  const int st = r >> 2, ot = r & 3;
  const int s0 = st * 64, o0 = ot * 64;

  __shared__ float Fs[64][129];
  __shared__ float Wt[64][129];
  __shared__ int   sIdx[64];
  __shared__ float sSub[64], sSc[64];

  if (tid < 64) sIdx[tid] = idxw[b*NS_ + s0 + tid];
  if (tid >= 64 && tid < 128) {
    const int oo = tid - 64;
    sSub[oo] = stats[((size_t)(b*COUT_ + o0 + oo))*2 + 0];
    sSc[oo]  = stats[((size_t)(b*COUT_ + o0 + oo))*2 + 1];
  }
  __syncthreads();
  {
    const int row = tid >> 2;   // 0..63
    const int q   = tid & 3;
    const float* fsrc = features + ((size_t)b*N_ + sIdx[row]) * CIN_;
    const float* wsrc = W + (size_t)(o0 + row) * CIN_;
    #pragma unroll
    for (int v = 0; v < 8; ++v) {
      const int c = q*4 + v*16;
      const float4 fv = *(const float4*)(fsrc + c);
      const float4 wv = *(const float4*)(wsrc + c);
      Fs[row][c+0]=fv.x; Fs[row][c+1]=fv.y; Fs[row][c+2]=fv.z; Fs[row][c+3]=fv.w;
      Wt[row][c+0]=wv.x; Wt[row][c+1]=wv.y; Wt[row][c+2]=wv.z; Wt[row][c+3]=wv.w;
    }
  }
  __syncthreads();

  const int ts = tid >> 4, to = tid & 15;
  float acc[4][4];
  #pragma unroll
  for (int i = 0; i < 4; ++i)
    #pragma unroll
    for (int j = 0; j < 4; ++j) acc[i][j] = 0.f;

  #pragma unroll 4
  for (int k = 0; k < CIN_; ++k) {
    const float a0 = Fs[ts*4+0][k], a1 = Fs[ts*4+1][k], a2 = Fs[ts*4+2][k], a3 = Fs[ts*4+3][k];
    const float w0 = Wt[to*4+0][k], w1 = Wt[to*4+1][k], w2 = Wt[to*4+2][k], w3 = Wt[to*4+3][k];
    acc[0][0]=fmaf(a0,w0,acc[0][0]); acc[0][1]=fmaf(a0,w1,acc[0][1]); acc[0][2]=fmaf(a0,w2,acc[0][2]); acc[0][3]=fmaf(a0,w3,acc[0][3]);
    acc[1][0]=fmaf(a1,w0,acc[1][0]); acc[1][1]=fmaf(a1,w1,acc[1][1]); acc[1][2]=fmaf(a1,w2,acc[1][2]); acc[1][3]=fmaf(a1,w3,acc[1][3]);
    acc[2][0]=fmaf(a2,w0,acc[2][0]); acc[2][1]=fmaf(a2,w1,acc[2][1]); acc[2][2]=fmaf(a2,w2,acc[2][2]); acc[2][3]=fmaf(a2,w3,acc[2][3]);
    acc[3][0]=fmaf(a3,w0,acc[3][0]); acc[3][1]=fmaf(a3,w1,acc[3][1]); acc[3][2]=fmaf(a3,w2,acc[3][2]); acc[3][3]=fmaf(a3,w3,acc[3][3]);
  }

  #pragma unroll
  for (int i = 0; i < 4; ++i) {
    float4 o4;
    o4.x = fmaxf((acc[i][0] - sSub[to*4+0]) * sSc[to*4+0], 0.f);
    o4.y = fmaxf((acc[i][1] - sSub[to*4+1]) * sSc[to*4+1], 0.f);
    o4.z = fmaxf((acc[i][2] - sSub[to*4+2]) * sSc[to*4+2], 0.f);
    o4.w = fmaxf((acc[i][3] - sSub[to*4+3]) * sSc[to*4+3], 0.f);
    *(float4*)&outF[((size_t)b*NS_ + s0 + ts*4 + i)*COUT_ + o0 + to*4] = o4;
  }
}

extern "C" void kernel_launch(void* const* d_in, const int* in_sizes, int n_in,
                              void* d_out, int out_size, void* d_ws, size_t ws_size,
                              hipStream_t stream) {
  (void)in_sizes; (void)n_in; (void)out_size; (void)ws_size;
  const float* points   = (const float*)d_in[0];
  const float* features = (const float*)d_in[1];
  const float* W        = (const float*)d_in[2];
  const float* bias     = (const float*)d_in[3];
  float* out  = (float*)d_out;
  float* outP = out;
  float* outF = out + (size_t)B_*NS_*3;

  char* ws = (char*)d_ws;
  int*   idxw  = (int*)  (ws + 0);        // 131072 B
  float* Gred  = (float*)(ws + 131072);   // 524288 B
  float* Sred  = (float*)(ws + 655360);   // 4096 B
  float* stats = (float*)(ws + 659456);   // 16384 B

  k1_fps_gram<<<dim3(B_ + B_),  dim3(512),  0, stream>>>(points, features, outP, idxw, Gred, Sred);
  k2b_stats  <<<dim3(B_*COUT_), dim3(CIN_), 0, stream>>>(Gred, Sred, W, bias, stats);
  k3_out     <<<dim3(B_*256),   dim3(256),  0, stream>>>(features, W, idxw, stats, outF);
}